// Round 1
// baseline (1851.174 us; speedup 1.0000x reference)
//
#include <hip/hip_runtime.h>
#include <math.h>
#include <stdint.h>

// Problem constants
#define DD 500
#define BB 512
#define KP 1536        // split-K total: [Ah(512) | Al(512) | Ah(512)] x [Wh | Wh | Wl]
// N layout (t>=1):  [r: x@(Wih_r+Whh_r) | z: x@(Wih_z+Whh_z) | i_n: x@Wih_n | h_n: x@Whh_n]
//   cols [0,500) r, [512,1012) z, [1024,1524) i_n, [1536,2036) h_n, pads zero-weighted.
// t=0 uses Wp0 whose r/z blocks are Wih only (h=0 -> gh contributes biases alone).
#define NW 2048        // padded N
#define NSTRIPS 64     // n-strips of 32
#define MSTRIPS 16     // m-strips of 32
#define KSTEPS  96     // ksteps of 16
#define NELEM (BB*DD)

typedef _Float16 f16;
typedef _Float16 f16x8 __attribute__((ext_vector_type(8)));
typedef float    f32x16 __attribute__((ext_vector_type(16)));

// Fragment-order layout (both Ap and Wp):
//   elem(strip, kstep, ln, j)  at  ((strip*KSTEPS + kstep)*64 + ln)*8 + j
//   maps to  row = strip*32 + (ln&31),  k = kstep*16 + (ln>>5)*8 + j
// which is exactly the mfma_f32_32x32x16_f16 A/B operand layout.

__device__ __forceinline__ bool frozen(const float* slots, float thr, int t) {
    bool f = false;
    for (int i = 0; i < t; ++i) f |= (slots[i] > thr);
    return f;
}

// ---------------------------------------------------------------------------
// Wp0 (t=0) and Wp1 (t>=1) in frag order. k-blocks of 512: [Wh | Wh | Wl].
// seg = n>>9: 0 -> r rows, 1 -> z rows, 2 -> i_n rows (Wih), 3 -> h_n rows (Whh).
// Wp0: seg0/1 = Wih only.  Wp1: seg0/1 = Wih + Whh.  seg2/3 identical in both.
// ---------------------------------------------------------------------------
__global__ __launch_bounds__(256) void conv_w(const float* __restrict__ Wih,
                                              const float* __restrict__ Whh,
                                              f16* __restrict__ Wp0,
                                              f16* __restrict__ Wp1)
{
    int p = blockIdx.x * 256 + threadIdx.x;    // (strip, kstep, ln)
    const int ln = p & 63; p >>= 6;
    const int kstep = p % KSTEPS;
    const int strip = p / KSTEPS;              // 0..63
    const int n = strip * 32 + (ln & 31);      // 0..2047
    const int kb0 = kstep * 16 + (ln >> 5) * 8;
    const int blk = kb0 >> 9, bk0 = kb0 & 511;
    const int seg = n >> 9;                    // 0..3
    const int dseg = n & 511;
    const float* pih = 0;
    const float* phh = 0;
    if (dseg < 500) {
        if (seg == 0)      { pih = Wih + (size_t)dseg * DD;
                             phh = Whh + (size_t)dseg * DD; }
        else if (seg == 1) { pih = Wih + (size_t)(500 + dseg) * DD;
                             phh = Whh + (size_t)(500 + dseg) * DD; }
        else if (seg == 2) { pih = Wih + (size_t)(1000 + dseg) * DD; }
        else               { phh = Whh + (size_t)(1000 + dseg) * DD; }
    }
    f16 o0[8], o1[8];
    #pragma unroll
    for (int j = 0; j < 8; ++j) {
        const int bk = bk0 + j;
        float vi = 0.f, vh = 0.f;
        if (bk < DD) {
            if (pih) vi = pih[bk];
            if (phh) vh = phh[bk];
        }
        const float v0 = (seg == 3) ? vh : vi;           // Wp0 value
        const float v1 = (seg <= 1) ? (vi + vh) : v0;    // Wp1 value
        f16 h0 = (f16)v0;
        f16 h1 = (f16)v1;
        o0[j] = (blk == 2) ? (f16)(v0 - (float)h0) : h0;
        o1[j] = (blk == 2) ? (f16)(v1 - (float)h1) : h1;
    }
    const size_t off = ((size_t)(strip * KSTEPS + kstep) * 64 + ln) * 8;
    *(uint4*)(Wp0 + off) = *(uint4*)o0;
    *(uint4*)(Wp1 + off) = *(uint4*)o1;
}

// ---------------------------------------------------------------------------
// Ap (frag order) from initial state. k-blocks: [Ah | Al | Ah]
// ---------------------------------------------------------------------------
__global__ __launch_bounds__(256) void conv_a(const float* __restrict__ S,
                                              f16* __restrict__ Ap)
{
    int p = blockIdx.x * 256 + threadIdx.x;    // (mstrip, kstep, ln)
    const int ln = p & 63; p >>= 6;
    const int kstep = p % KSTEPS;
    const int strip = p / KSTEPS;              // 0..15
    const int b = strip * 32 + (ln & 31);
    const int kb0 = kstep * 16 + (ln >> 5) * 8;
    const int blk = kb0 >> 9, bk0 = kb0 & 511;
    f16 out[8];
    #pragma unroll
    for (int j = 0; j < 8; ++j) {
        const int bk = bk0 + j;
        float v = (bk < DD) ? S[(size_t)b * DD + bk] : 0.f;
        f16 hi = (f16)v;
        out[j] = (blk == 1) ? (f16)(v - (float)hi) : hi;
    }
    *(uint4*)(Ap + ((size_t)(strip * KSTEPS + kstep) * 64 + ln) * 8) = *(uint4*)out;
}

// ---------------------------------------------------------------------------
// GEMM: C[512 x 2048] += Ap * Wp^T over one K-half (768). Pure register
// streaming: each wave owns a 64x32 output tile (2 accs), streams its own
// A (2 strips) and B fragments global->reg through 16-deep rings (lookahead
// 16 ksteps = 256 cyc > L2 latency). No LDS, no __syncthreads. Block 256 thr
// = 4 waves (2m x 2n), tile 128x64, grid (32, 4, 2) = 256 blocks = 1/CU.
// ---------------------------------------------------------------------------
__global__ __launch_bounds__(256) void gemm_f16(
    const f16* __restrict__ Ap, const f16* __restrict__ Wp,
    float* __restrict__ C0, float* __restrict__ C1,
    const float* __restrict__ slots, const float* __restrict__ bc,
    const int* __restrict__ rec, int t)
{
    if (t >= rec[0]) return;
    const float thr = bc[0] * (float)NELEM;
    if (frozen(slots, thr, t)) return;

    const int bn = blockIdx.x;        // 0..31  (n-strip pair)
    const int bm = blockIdx.y;        // 0..3   (4 m-strips = 128 rows)
    const int kh = blockIdx.z;        // 0..1   (K half)
    float* __restrict__ C = kh ? C1 : C0;

    const int tid = threadIdx.x, wv = tid >> 6, ln = tid & 63;
    const int wm = wv & 1;            // m half (64 rows = 2 m-strips)
    const int wn = wv >> 1;           // n strip within pair
    const int ks0 = kh * 48;          // kstep base for this half

    // Per-wave stream bases (frag order; consecutive ksteps are 512 f16 apart)
    const f16* Bp  = Wp + ((size_t)((bn * 2 + wn) * KSTEPS + ks0) * 64 + ln) * 8;
    const f16* Ap0 = Ap + ((size_t)((bm * 4 + 2 * wm)     * KSTEPS + ks0) * 64 + ln) * 8;
    const f16* Ap1 = Ap + ((size_t)((bm * 4 + 2 * wm + 1) * KSTEPS + ks0) * 64 + ln) * 8;

    uint4 rA0[16], rA1[16], rB[16];
    #pragma unroll
    for (int i = 0; i < 16; ++i) {
        rA0[i] = *(const uint4*)(Ap0 + (size_t)i * 512);
        rA1[i] = *(const uint4*)(Ap1 + (size_t)i * 512);
        rB[i]  = *(const uint4*)(Bp  + (size_t)i * 512);
    }

    f32x16 acc0 = {}, acc1 = {};
    #pragma unroll
    for (int ks = 0; ks < 48; ++ks) {
        const int sl = ks & 15;                    // compile-time (full unroll)
        f16x8 a0 = *(f16x8*)&rA0[sl];
        f16x8 a1 = *(f16x8*)&rA1[sl];
        f16x8 b  = *(f16x8*)&rB[sl];
        acc0 = __builtin_amdgcn_mfma_f32_32x32x16_f16(a0, b, acc0, 0, 0, 0);
        acc1 = __builtin_amdgcn_mfma_f32_32x32x16_f16(a1, b, acc1, 0, 0, 0);
        if (ks < 32) {                             // refill 16 ksteps ahead
            rA0[sl] = *(const uint4*)(Ap0 + (size_t)(ks + 16) * 512);
            rA1[sl] = *(const uint4*)(Ap1 + (size_t)(ks + 16) * 512);
            rB[sl]  = *(const uint4*)(Bp  + (size_t)(ks + 16) * 512);
        }
    }

    // epilogue: C/D layout col=lane&31, row=(r&3)+8*(r>>2)+4*(lane>>5)
    const int col = bn * 64 + wn * 32 + (ln & 31);
    const int rb0 = (bm * 4 + 2 * wm) * 32 + 4 * (ln >> 5);
    #pragma unroll
    for (int r = 0; r < 16; ++r) {
        const int row = rb0 + (r & 3) + 8 * (r >> 2);
        C[(size_t)row * NW + col]        = acc0[r];
        C[(size_t)(row + 32) * NW + col] = acc1[r];
    }
}

// ---------------------------------------------------------------------------
// gates + h update + Ap refresh (frag order) + mean reduce into slots[t]
// C cols: r = d, z = 512+d, i_n = 1024+d, h_n = 1536+d.
// r/z columns already hold the summed x@(Wih+Whh) for t>=1 (x == h), so both
// biases are added here. t=0: r/z from Wih-only Wp0, h_n = b_hh_n, h_prev = 0.
// ---------------------------------------------------------------------------
__global__ __launch_bounds__(512) void gru_ew(
    const float* __restrict__ C0, const float* __restrict__ C1,
    const float* __restrict__ bih, const float* __restrict__ bhh,
    float* __restrict__ h, f16* __restrict__ Ap, float* __restrict__ slots,
    const float* __restrict__ bc, const int* __restrict__ rec, int t)
{
    if (t >= rec[0]) return;
    const float thr = bc[0] * (float)NELEM;
    if (frozen(slots, thr, t)) return;

    const int b = blockIdx.x;
    const int d = threadIdx.x;
    float hnew = 0.0f;
    if (d < DD) {
        const float* Cb0 = C0 + (size_t)b * NW;
        const float* Cb1 = C1 + (size_t)b * NW;
        float cr  = Cb0[d]        + Cb1[d];
        float cz  = Cb0[512 + d]  + Cb1[512 + d];
        float cin = Cb0[1024 + d] + Cb1[1024 + d];
        float r = 1.0f / (1.0f + expf(-(cr + bih[d] + bhh[d])));
        float z = 1.0f / (1.0f + expf(-(cz + bih[500 + d] + bhh[500 + d])));
        float inn = cin + bih[1000 + d];
        float hn  = bhh[1000 + d];
        float hp  = 0.0f;
        if (t > 0) {   // at t=0 true h is 0; h_n column holds garbage, unused
            hn += Cb0[1536 + d] + Cb1[1536 + d];
            hp = h[b * DD + d];
        }
        float n = tanhf(inn + r * hn);
        hnew = (1.0f - z) * n + z * hp;
        h[b * DD + d] = hnew;
        // refresh Ap (frag order): k = d (hi), 512+d (lo), 1024+d (hi)
        const int ms = b >> 5, lm = b & 31;
        f16 hi = (f16)hnew;
        f16 lo = (f16)(hnew - (float)hi);
        {
            int k = d, kstep = k >> 4, half = (k >> 3) & 1, j = k & 7;
            Ap[((size_t)(ms * KSTEPS + kstep) * 64 + half * 32 + lm) * 8 + j] = hi;
        }
        {
            int k = 512 + d, kstep = k >> 4, half = (k >> 3) & 1, j = k & 7;
            Ap[((size_t)(ms * KSTEPS + kstep) * 64 + half * 32 + lm) * 8 + j] = lo;
        }
        {
            int k = 1024 + d, kstep = k >> 4, half = (k >> 3) & 1, j = k & 7;
            Ap[((size_t)(ms * KSTEPS + kstep) * 64 + half * 32 + lm) * 8 + j] = hi;
        }
    }
    // block reduce sum(h_new) -> slots[t]
    float v = hnew;
    #pragma unroll
    for (int off = 32; off > 0; off >>= 1) v += __shfl_down(v, off, 64);
    __shared__ float red[8];
    const int lane = threadIdx.x & 63;
    const int wid  = threadIdx.x >> 6;
    if (lane == 0) red[wid] = v;
    __syncthreads();
    if (wid == 0) {
        float s2 = (lane < 8) ? red[lane] : 0.0f;
        #pragma unroll
        for (int off = 4; off > 0; off >>= 1) s2 += __shfl_down(s2, off, 64);
        if (lane == 0) atomicAdd(&slots[t], s2);
    }
}

extern "C" void kernel_launch(void* const* d_in, const int* in_sizes, int n_in,
                              void* d_out, int out_size, void* d_ws, size_t ws_size,
                              hipStream_t stream)
{
    const float* state = (const float*)d_in[0];
    const float* Wih   = (const float*)d_in[1];
    const float* Whh   = (const float*)d_in[2];
    const float* bih   = (const float*)d_in[3];
    const float* bhh   = (const float*)d_in[4];
    const float* bc    = (const float*)d_in[5];
    const int*   rec   = (const int*)d_in[6];

    char* ws = (char*)d_ws;
    float* slots = (float*)ws;                                        // 256 B
    f16*   Ap    = (f16*)(ws + 256);                                  // 1.5 MB
    f16*   Wp0   = Ap  + (size_t)MSTRIPS * KSTEPS * 64 * 8;           // 6.3 MB
    f16*   Wp1   = Wp0 + (size_t)NSTRIPS * KSTEPS * 64 * 8;           // 6.3 MB
    float* C0    = (float*)(Wp1 + (size_t)NSTRIPS * KSTEPS * 64 * 8); // 4.2 MB
    float* C1    = C0 + (size_t)BB * NW;                              // 4.2 MB
    float* out   = (float*)d_out;

    hipMemsetAsync(slots, 0, 256, stream);
    // rec==0 robustness: output = state if no iteration runs
    hipMemcpyAsync(out, state, (size_t)NELEM * sizeof(float),
                   hipMemcpyDeviceToDevice, stream);

    conv_w<<<dim3(NSTRIPS * KSTEPS * 64 / 256), 256, 0, stream>>>(Wih, Whh, Wp0, Wp1);
    conv_a<<<dim3(MSTRIPS * KSTEPS * 64 / 256), 256, 0, stream>>>(state, Ap);

    const int ITERS = 64;  // device-side guard handles rec[0] < 64
    for (int t = 0; t < ITERS; ++t) {
        const f16* W = (t == 0) ? Wp0 : Wp1;
        gemm_f16<<<dim3(32, 4, 2), 256, 0, stream>>>(Ap, W, C0, C1,
                                                     slots, bc, rec, t);
        gru_ew<<<dim3(BB), 512, 0, stream>>>(C0, C1, bih, bhh, out, Ap,
                                             slots, bc, rec, t);
    }
}